// Round 4
// baseline (159.670 us; speedup 1.0000x reference)
//
#include <hip/hip_runtime.h>
#include <math.h>

// Problem constants (B=64, S=8192, D=32), fp32 in/out.
#define B_ 64
#define S_ 8192
#define D_ 32

__device__ __forceinline__ void load_lds16(const float* g, float* l) {
    __builtin_amdgcn_global_load_lds(
        (const __attribute__((address_space(1))) void*)g,
        (__attribute__((address_space(3))) void*)l,
        16, 0, 0);
}

// ---------------- Kernel 1: per-batch Gram matrix G = x^T x ----------------
// 1024 blocks = B * 16 chunks of 512 rows; 256 thr (4 waves); 4 double-buffered
// sub-tiles of 128 rows (2x16KB LDS).
// Lane layout: rg=lane>>4 (row-group 0..3), l16=lane&15 owns an 8x8 G block
// (bi=(l16>>2)*8, bj=(l16&3)*8). One ds_read_b128 per row per lane-pair vs the
// old 4x4 scheme's two -> LDS return-bus traffic halves (1024 B/row/wave).
// XOR granule swizzle (T21 both-sides): stage with pre-swizzled global source
// (granule c ^ (r&7)), read with the same XOR -> row-groups hit distinct
// bank-groups (<=2 distinct addrs/group + broadcasts = free).
#define GCH 16
#define GSUB 128
#define GNSUB 4

__global__ __launch_bounds__(256) void gram_k(const float* __restrict__ x,
                                              float* __restrict__ gpart) {
    __shared__ float tile[2][GSUB * D_];     // 2 x 16 KB
    const int blk = blockIdx.x;              // 1024
    const int b   = blk >> 4;
    const int ch  = blk & 15;
    const int t   = threadIdx.x;
    const int w   = t >> 6;
    const int lane = t & 63;
    const int rg  = lane >> 4;
    const int l16 = lane & 15;
    const int bi  = (l16 >> 2) << 3;         // 0,8,16,24
    const int bj  = (l16 & 3) << 3;
    const int gi0 = bi >> 2;                 // even granule index
    const int gj0 = bj >> 2;

    const float* xb = x + ((size_t)b * S_ + (size_t)ch * (GSUB * GNSUB)) * D_;

    float acc[8][8] = {};

    // stage sub 0
    #pragma unroll
    for (int it = 0; it < 4; ++it) {
        const int p = it * 256 + t;          // linear LDS granule
        const int r = p >> 3, c = p & 7;
        const int sg = r * 8 + (c ^ (r & 7));
        load_lds16(xb + sg * 4, &tile[0][p * 4]);
    }
    __syncthreads();

    for (int s = 0; s < GNSUB; ++s) {
        if (s + 1 < GNSUB) {                 // prefetch next sub into other buf
            const float* src = xb + (size_t)(s + 1) * GSUB * D_;
            #pragma unroll
            for (int it = 0; it < 4; ++it) {
                const int p = it * 256 + t;
                const int r = p >> 3, c = p & 7;
                const int sg = r * 8 + (c ^ (r & 7));
                load_lds16(src + sg * 4, &tile[(s + 1) & 1][p * 4]);
            }
        }
        const float* tl = tile[s & 1];
        #pragma unroll
        for (int it = 0; it < 8; ++it) {
            const int r  = w * 32 + it * 4 + rg;
            const int sw = r & 7;
            const float* row = tl + r * D_;
            const float4 xiA = *(const float4*)(row + ((gi0 ^ sw) << 2));
            const float4 xiB = *(const float4*)(row + (((gi0 + 1) ^ sw) << 2));
            const float4 xjA = *(const float4*)(row + ((gj0 ^ sw) << 2));
            const float4 xjB = *(const float4*)(row + (((gj0 + 1) ^ sw) << 2));
            const float xi[8] = {xiA.x, xiA.y, xiA.z, xiA.w,
                                 xiB.x, xiB.y, xiB.z, xiB.w};
            const float xj[8] = {xjA.x, xjA.y, xjA.z, xjA.w,
                                 xjB.x, xjB.y, xjB.z, xjB.w};
            #pragma unroll
            for (int a = 0; a < 8; ++a)
                #pragma unroll
                for (int c2 = 0; c2 < 8; ++c2)
                    acc[a][c2] = fmaf(xi[a], xj[c2], acc[a][c2]);
        }
        __syncthreads();
    }

    // Intra-wave reduce across the 4 row-groups (lane bits 4,5); static idx.
    #pragma unroll
    for (int a = 0; a < 8; ++a)
        #pragma unroll
        for (int c2 = 0; c2 < 8; ++c2) {
            float v = acc[a][c2];
            v += __shfl_xor(v, 16, 64);
            v += __shfl_xor(v, 32, 64);
            acc[a][c2] = v;
        }

    // Cross-wave reduce via red[4][1024] in tile (16 KB), then write G partial.
    float* red = &tile[0][0];
    __syncthreads();
    if (rg == 0) {
        #pragma unroll
        for (int a = 0; a < 8; ++a)
            #pragma unroll
            for (int c2 = 0; c2 < 8; c2 += 4) {
                *(float4*)(red + w * 1024 + l16 * 64 + a * 8 + c2) =
                    make_float4(acc[a][c2], acc[a][c2 + 1],
                                acc[a][c2 + 2], acc[a][c2 + 3]);
            }
    }
    __syncthreads();
    #pragma unroll
    for (int e4 = 0; e4 < 4; ++e4) {
        const int e = e4 * 256 + t;
        const float sv = red[e] + red[1024 + e] + red[2048 + e] + red[3072 + e];
        const int li = e >> 6, a = (e >> 3) & 7, c2 = e & 7;
        const int i = ((li >> 2) << 3) + a;
        const int j = ((li & 3) << 3) + c2;
        gpart[(size_t)blk * 1024 + i * 32 + j] = sv;
    }
}

// ------------- Kernel 2: tiny per-batch scores/softmax and M ---------------
__global__ __launch_bounds__(1024) void attn_small(const float* __restrict__ gpart,
                                                   const float* __restrict__ Wq,
                                                   const float* __restrict__ Wk,
                                                   const float* __restrict__ Wv,
                                                   float* __restrict__ M) {
    __shared__ float GL[32][33], WqL[32][33], WkL[32][33], WvL[32][33];
    __shared__ float T1L[32][33], PL[32][33];
    __shared__ float mcol[32], scol[32];

    const int b = blockIdx.x;
    const int t = threadIdx.x;
    const int r = t >> 5, c = t & 31;

    float g = 0.f;
    #pragma unroll
    for (int cc = 0; cc < GCH; ++cc)
        g += gpart[(size_t)(b * GCH + cc) * 1024 + t];
    GL[r][c]  = g;
    WqL[r][c] = Wq[t];
    WkL[r][c] = Wk[t];
    WvL[r][c] = Wv[t];
    __syncthreads();

    float t1 = 0.f;
    #pragma unroll
    for (int e = 0; e < 32; ++e) t1 = fmaf(GL[r][e], WkL[e][c], t1);
    T1L[r][c] = t1;
    __syncthreads();

    float p = 0.f;
    #pragma unroll
    for (int d = 0; d < 32; ++d) p = fmaf(WqL[d][r], T1L[d][c], p);
    PL[r][c] = p;
    __syncthreads();

    if (t < 32) {
        float m = -INFINITY;
        #pragma unroll
        for (int q = 0; q < 32; ++q) m = fmaxf(m, PL[q][t]);
        float s = 0.f;
        #pragma unroll
        for (int q = 0; q < 32; ++q) s += __expf(PL[q][t] - m);
        mcol[t] = m;
        scol[t] = 1.0f / s;
    }
    __syncthreads();
    const float sc = __expf(PL[r][c] - mcol[c]) * scol[c];
    PL[r][c] = sc;
    __syncthreads();

    float mm = 0.f;
    #pragma unroll
    for (int k = 0; k < 32; ++k) mm = fmaf(WvL[r][k], PL[c][k], mm);
    M[(size_t)b * 1024 + t] = mm;    // M[b][d][q]
}

// ---------------- Kernel 3: out[b][q][s] = sum_d x[b][s][d] * M[b][d][q] ----
// (unchanged from passing round-3 kernel: staged + T21 swizzle, lane t owns
// row t, M via scalarized uniform loads, 32 lane-contiguous stores.)
#define OUT_ROWS 256

__global__ __launch_bounds__(256) void out_k(const float* __restrict__ x,
                                             const float* __restrict__ M,
                                             float* __restrict__ out) {
    __shared__ float tile[OUT_ROWS * D_];  // 32 KB
    const int blk = blockIdx.x;            // 2048
    const int b   = blk >> 5;
    const int ch  = blk & 31;
    const int t   = threadIdx.x;

    const float* src = x + ((size_t)b * S_ + (size_t)ch * OUT_ROWS) * D_;
    #pragma unroll
    for (int k = 0; k < 8; ++k) {
        const int g  = k * 256 + t;
        const int r  = g >> 3, j = g & 7;
        const int gs = r * 8 + (j ^ (r & 7));
        load_lds16(src + gs * 4, tile + g * 4);
    }
    __syncthreads();

    const float* Mb = M + (size_t)b * 1024;
    float acc[32] = {};
    const int r = t;
    #pragma unroll
    for (int j = 0; j < 8; ++j) {
        const int pg = r * 8 + (j ^ (r & 7));
        const float4 xv = *(const float4*)(tile + pg * 4);
        const float xd[4] = {xv.x, xv.y, xv.z, xv.w};
        #pragma unroll
        for (int dd = 0; dd < 4; ++dd) {
            const int d = j * 4 + dd;
            #pragma unroll
            for (int q = 0; q < 32; ++q)
                acc[q] = fmaf(Mb[d * 32 + q], xd[dd], acc[q]);
        }
    }

    const int s = ch * OUT_ROWS + r;
    float* ob = out + (size_t)b * D_ * S_ + s;
    #pragma unroll
    for (int q = 0; q < 32; ++q)
        ob[(size_t)q * S_] = acc[q];
}

extern "C" void kernel_launch(void* const* d_in, const int* in_sizes, int n_in,
                              void* d_out, int out_size, void* d_ws, size_t ws_size,
                              hipStream_t stream) {
    const float* x  = (const float*)d_in[0];
    const float* Wq = (const float*)d_in[1];
    const float* Wk = (const float*)d_in[2];
    const float* Wv = (const float*)d_in[3];
    float* out = (float*)d_out;

    // ws layout: gpart[1024][1024] (4 MiB) then M[64][1024] (256 KiB).
    float* gpart = (float*)d_ws;
    float* M     = gpart + (size_t)B_ * GCH * 1024;

    gram_k<<<B_ * GCH, 256, 0, stream>>>(x, gpart);
    attn_small<<<B_, 1024, 0, stream>>>(gpart, Wq, Wk, Wv, M);
    out_k<<<B_ * 32, 256, 0, stream>>>(x, M, out);
}

// Round 7
// 155.209 us; speedup vs baseline: 1.0287x; 1.0287x over previous
//
#include <hip/hip_runtime.h>
#include <math.h>

// Problem constants (B=64, S=8192, D=32), fp32 in/out.
#define B_ 64
#define S_ 8192
#define D_ 32

__device__ __forceinline__ void load_lds16(const float* g, float* l) {
    __builtin_amdgcn_global_load_lds(
        (const __attribute__((address_space(1))) void*)g,
        (__attribute__((address_space(3))) void*)l,
        16, 0, 0);
}

// ---------------- Kernel 1: per-batch Gram matrix G = x^T x ----------------
// 1024 blocks (b, ch16 of 512 rows) x 256 thr (4 waves), 16 KB LDS single
// buffer, 4 subtiles of 128 rows, barrier-staged (PROVEN round-3 pattern).
// 4x4 lane blocks (acc=16 regs, launch_bounds(256,8) -> VGPR<=64 -> up to
// 32 waves/CU; LDS allows 10 blocks, waves cap at 8 blocks/CU).
// Whole wave reads the SAME row -> 8-distinct-granule broadcast, conflict-
// free, linear LDS, no swizzle.
#define GCH 16

__global__ __launch_bounds__(256, 8) void gram_k(const float* __restrict__ x,
                                                 float* __restrict__ gpart) {
    __shared__ float tile[128 * D_];        // 16 KB
    const int blk = blockIdx.x;             // 1024
    const int b   = blk >> 4;
    const int ch  = blk & 15;
    const int t   = threadIdx.x;
    const int w   = t >> 6;
    const int l   = t & 63;
    const int i0  = ((l >> 3) & 7) << 2;    // 0,4,...,28
    const int j0  = (l & 7) << 2;

    const float* xb = x + ((size_t)b * S_ + (size_t)ch * 512) * D_;

    float acc[4][4] = {};
    for (int s = 0; s < 4; ++s) {
        const float* src = xb + (size_t)s * 128 * D_;
        #pragma unroll
        for (int k = 0; k < 4; ++k) {
            const int g = k * 256 + t;      // linear granule 0..1023
            load_lds16(src + g * 4, tile + g * 4);
        }
        __syncthreads();                    // compiler drains vmcnt before barrier

        #pragma unroll 4
        for (int it = 0; it < 32; ++it) {
            const int r = w * 32 + it;      // wave-private rows
            const float* row = tile + r * D_;
            const float4 xi = *(const float4*)(row + i0);
            const float4 xj = *(const float4*)(row + j0);
            const float xiv[4] = {xi.x, xi.y, xi.z, xi.w};
            const float xjv[4] = {xj.x, xj.y, xj.z, xj.w};
            #pragma unroll
            for (int a = 0; a < 4; ++a)
                #pragma unroll
                for (int c = 0; c < 4; ++c)
                    acc[a][c] = fmaf(xiv[a], xjv[c], acc[a][c]);
        }
        __syncthreads();                    // before overwriting tile
    }

    // Cross-wave reduce: red[4][1024] reuses tile (exactly 16 KB).
    float* red = tile;
    #pragma unroll
    for (int a = 0; a < 4; ++a)
        #pragma unroll
        for (int c = 0; c < 4; ++c)
            red[w * 1024 + l * 16 + a * 4 + c] = acc[a][c];
    __syncthreads();

    #pragma unroll
    for (int e4 = 0; e4 < 4; ++e4) {
        const int e = e4 * 256 + t;
        const float sv = red[e] + red[1024 + e] + red[2048 + e] + red[3072 + e];
        const int ll = e >> 4, ee = e & 15;
        const int i = (((ll >> 3) & 7) << 2) + (ee >> 2);
        const int j = ((ll & 7) << 2) + (ee & 3);
        gpart[(size_t)blk * 1024 + i * 32 + j] = sv;
    }
}

// ------------- Kernel 2: tiny per-batch scores/softmax and M ---------------
// (unchanged from rounds 2-4, always passed)
__global__ __launch_bounds__(1024) void attn_small(const float* __restrict__ gpart,
                                                   const float* __restrict__ Wq,
                                                   const float* __restrict__ Wk,
                                                   const float* __restrict__ Wv,
                                                   float* __restrict__ M) {
    __shared__ float GL[32][33], WqL[32][33], WkL[32][33], WvL[32][33];
    __shared__ float T1L[32][33], PL[32][33];
    __shared__ float mcol[32], scol[32];

    const int b = blockIdx.x;
    const int t = threadIdx.x;
    const int r = t >> 5, c = t & 31;

    float g = 0.f;
    #pragma unroll
    for (int cc = 0; cc < GCH; ++cc)
        g += gpart[(size_t)(b * GCH + cc) * 1024 + t];
    GL[r][c]  = g;
    WqL[r][c] = Wq[t];
    WkL[r][c] = Wk[t];
    WvL[r][c] = Wv[t];
    __syncthreads();

    float t1 = 0.f;
    #pragma unroll
    for (int e = 0; e < 32; ++e) t1 = fmaf(GL[r][e], WkL[e][c], t1);
    T1L[r][c] = t1;
    __syncthreads();

    float p = 0.f;
    #pragma unroll
    for (int d = 0; d < 32; ++d) p = fmaf(WqL[d][r], T1L[d][c], p);
    PL[r][c] = p;
    __syncthreads();

    if (t < 32) {
        float m = -INFINITY;
        #pragma unroll
        for (int q = 0; q < 32; ++q) m = fmaxf(m, PL[q][t]);
        float s = 0.f;
        #pragma unroll
        for (int q = 0; q < 32; ++q) s += __expf(PL[q][t] - m);
        mcol[t] = m;
        scol[t] = 1.0f / s;
    }
    __syncthreads();
    const float sc = __expf(PL[r][c] - mcol[c]) * scol[c];
    PL[r][c] = sc;
    __syncthreads();

    float mm = 0.f;
    #pragma unroll
    for (int k = 0; k < 32; ++k) mm = fmaf(WvL[r][k], PL[c][k], mm);
    M[(size_t)b * 1024 + t] = mm;    // M[b][d][q]
}

// ---------------- Kernel 3: out[b][q][s] = sum_d x[b][s][d] * M[b][d][q] ----
// 4096 blocks (b, ch of 128 rows) x 128 thr, 16 KB LDS -> 10 blocks/CU
// (was 5 at 32 KB). Cooperative stage via global_load_lds with XOR-swizzled
// SOURCE (granule c ^ (r&7), involution) + same XOR on the ds_read_b128
// (T21 both-sides, byte-identical math to the PASSING round-3/4 kernel).
// Lane owns row t; M via uniform s_loads; 32 lane-contiguous stores.
__global__ __launch_bounds__(128, 8) void out_k(const float* __restrict__ x,
                                                const float* __restrict__ M,
                                                float* __restrict__ out) {
    __shared__ float tile[128 * D_];        // 16 KB
    const int blk = blockIdx.x;             // 4096
    const int b   = blk >> 6;
    const int ch  = blk & 63;
    const int t   = threadIdx.x;

    const float* src = x + ((size_t)b * S_ + (size_t)ch * 128) * D_;
    #pragma unroll
    for (int k = 0; k < 8; ++k) {
        const int g = k * 128 + t;          // linear LDS granule 0..1023
        const int r = g >> 3, c = g & 7;
        const int sg = r * 8 + (c ^ (r & 7));
        load_lds16(src + sg * 4, tile + g * 4);
    }
    __syncthreads();                        // vmcnt(0) drain + block sync

    const float* Mb = M + (size_t)b * 1024;
    float acc[32] = {};
    const int r = t;                        // row 0..127
    #pragma unroll
    for (int j = 0; j < 8; ++j) {
        const int pg = r * 8 + (j ^ (r & 7));
        const float4 xv = *(const float4*)(tile + pg * 4);
        const float xd[4] = {xv.x, xv.y, xv.z, xv.w};
        #pragma unroll
        for (int dd = 0; dd < 4; ++dd) {
            const int d = j * 4 + dd;
            #pragma unroll
            for (int q = 0; q < 32; ++q)
                acc[q] = fmaf(Mb[d * 32 + q], xd[dd], acc[q]);
        }
    }

    const int s = ch * 128 + t;
    float* ob = out + (size_t)b * D_ * S_ + s;
    #pragma unroll
    for (int q = 0; q < 32; ++q)
        ob[(size_t)q * S_] = acc[q];
}

extern "C" void kernel_launch(void* const* d_in, const int* in_sizes, int n_in,
                              void* d_out, int out_size, void* d_ws, size_t ws_size,
                              hipStream_t stream) {
    const float* x  = (const float*)d_in[0];
    const float* Wq = (const float*)d_in[1];
    const float* Wk = (const float*)d_in[2];
    const float* Wv = (const float*)d_in[3];
    float* out = (float*)d_out;

    // ws layout: gpart[1024][1024] (4 MiB) then M[64][1024] (256 KiB).
    float* gpart = (float*)d_ws;
    float* M     = gpart + (size_t)B_ * GCH * 1024;

    gram_k<<<B_ * GCH, 256, 0, stream>>>(x, gpart);
    attn_small<<<B_, 1024, 0, stream>>>(gpart, Wq, Wk, Wv, M);
    out_k<<<B_ * 64, 128, 0, stream>>>(x, M, out);
}